// Round 17
// baseline (161.867 us; speedup 1.0000x reference)
//
#include <hip/hip_runtime.h>
#include <hip/hip_bf16.h>

#define Bn 8
#define Nn 1024
#define Dn 256
#define Hn 4
#define HOn 64
#define Tn 5
#define WTR 80   // WT rows per head: 64 W^T cols + 10 Wa rows + 6 zero pad

typedef short bf16x8 __attribute__((ext_vector_type(8)));
typedef float f32x4 __attribute__((ext_vector_type(4)));

__device__ __forceinline__ float b2f(unsigned short u) {
    unsigned x = ((unsigned)u) << 16;
    float f;
    __builtin_memcpy(&f, &x, 4);
    return f;
}
__device__ __forceinline__ unsigned bfr(float f) {
    unsigned u;
    __builtin_memcpy(&u, &f, 4);
    return (u + 0x7FFFu + ((u >> 16) & 1u)) >> 16;
}
__device__ __forceinline__ unsigned short f2b(float f) { return (unsigned short)bfr(f); }

// ---------- fallback: signal "workspace too small" with out = 100.0 ----------
__global__ __launch_bounds__(256) void k_signal(float* __restrict__ out, int n) {
    int i = blockIdx.x * 256 + threadIdx.x;
    if (i < n) out[i] = 100.0f;
}

// ---------- kernel 0: WT [H][80][D] bf16: rows 0-63 = W^T, 64-73 = W.a_src|W.a_dst, 74-79 = 0
__global__ __launch_bounds__(256) void k_transpose_w(const float* __restrict__ W,
                                                     const float* __restrict__ a_src,
                                                     const float* __restrict__ a_dst,
                                                     unsigned short* __restrict__ WT) {
    __shared__ float tile[64][65];
    int h = blockIdx.x >> 2;
    int d0 = (blockIdx.x & 3) * 64;
    int c0 = threadIdx.x & 63;
    int r0 = threadIdx.x >> 6;  // 0..3
#pragma unroll
    for (int r = 0; r < 16; r++) {
        int d = r * 4 + r0;
        tile[d][c0] = W[((size_t)(h * Dn + d0 + d)) * HOn + c0];  // coalesced over e
    }
    __syncthreads();
#pragma unroll
    for (int r = 0; r < 16; r++) {
        int e = r * 4 + r0;
        WT[((size_t)(h * WTR + e)) * Dn + d0 + c0] = f2b(tile[c0][e]);
    }
    for (int t = r0; t < 2 * Tn; t += 4) {
        const float* av = (t < Tn) ? (a_src + (h * Tn + t) * HOn)
                                   : (a_dst + (h * Tn + t - Tn) * HOn);
        float s = 0.f;
#pragma unroll
        for (int e = 0; e < HOn; e++) s += tile[c0][e] * av[e];
        WT[((size_t)(h * WTR + 64 + t)) * Dn + d0 + c0] = f2b(s);
    }
    for (int rr = 74 + r0; rr < WTR; rr += 4)
        WT[((size_t)(h * WTR + rr)) * Dn + d0 + c0] = 0;
}

// ---------- kernel 1: h^T = W^T x X^T via MFMA + adj u8 packing ----------
__global__ __launch_bounds__(256) void k_proj(const float* __restrict__ X,
                                              const unsigned short* __restrict__ WT,
                                              const int* __restrict__ adj,
                                              unsigned short* __restrict__ hT,
                                              float* __restrict__ e_src,
                                              float* __restrict__ e_dst,
                                              unsigned* __restrict__ adjp) {
    int tid = threadIdx.x;
    int w = tid >> 6;
    int lane = tid & 63;
    int quad = lane >> 4;
    int l15 = lane & 15;
    int b = blockIdx.x >> 6;
    int i0 = (blockIdx.x & 63) * 16;
    int h = w;
    int bh = b * Hn + h;

    // pack this block's 16 adj rows to u8 (coalesced int4 loads / u32 stores)
    {
        const int* arow = adj + ((size_t)(b * Nn + i0)) * Nn;
        unsigned* aout = adjp + ((size_t)(b * Nn + i0)) * Nn / 4;
#pragma unroll 4
        for (int k = 0; k < 16; k++) {
            int idx = tid + k * 256;
            int4 v = *(const int4*)(arow + (size_t)idx * 4);
            unsigned pk = (unsigned)(v.x & 0xFF) | ((unsigned)(v.y & 0xFF) << 8) |
                          ((unsigned)(v.z & 0xFF) << 16) | ((unsigned)(v.w & 0xFF) << 24);
            aout[idx] = pk;
        }
    }

    bf16x8 Bx[8];
    const float* xf = X + ((size_t)(b * Nn + i0 + l15)) * Dn + quad * 8;
#pragma unroll
    for (int kc = 0; kc < 8; kc++) {
        union { bf16x8 v; unsigned u[4]; } uu;
        const float4* xp = (const float4*)(xf + kc * 32);
        float4 A0 = xp[0], A1 = xp[1];
        __hip_bfloat162 h0 = __float22bfloat162_rn(make_float2(A0.x, A0.y));
        __hip_bfloat162 h1 = __float22bfloat162_rn(make_float2(A0.z, A0.w));
        __hip_bfloat162 h2 = __float22bfloat162_rn(make_float2(A1.x, A1.y));
        __hip_bfloat162 h3 = __float22bfloat162_rn(make_float2(A1.z, A1.w));
        __builtin_memcpy(&uu.u[0], &h0, 4);
        __builtin_memcpy(&uu.u[1], &h1, 4);
        __builtin_memcpy(&uu.u[2], &h2, 4);
        __builtin_memcpy(&uu.u[3], &h3, 4);
        Bx[kc] = uu.v;
    }

    f32x4 acc[5] = {{0.f, 0.f, 0.f, 0.f}, {0.f, 0.f, 0.f, 0.f}, {0.f, 0.f, 0.f, 0.f},
                    {0.f, 0.f, 0.f, 0.f}, {0.f, 0.f, 0.f, 0.f}};
    const unsigned short* wbase = WT + (size_t)h * WTR * Dn;
#pragma unroll
    for (int kc = 0; kc < 8; kc++) {
#pragma unroll
        for (int et = 0; et < 5; et++) {
            bf16x8 Aw = *(const bf16x8*)(wbase + (size_t)(et * 16 + l15) * Dn + kc * 32 + quad * 8);
            acc[et] = __builtin_amdgcn_mfma_f32_16x16x32_bf16(Aw, Bx[kc], acc[et], 0, 0, 0);
        }
    }

#pragma unroll
    for (int et = 0; et < 4; et++) {
#pragma unroll
        for (int reg = 0; reg < 4; reg++) {
            int e = et * 16 + quad * 4 + reg;
            hT[((size_t)bh * HOn + e) * Nn + i0 + l15] = f2b(acc[et][reg]);
        }
    }
#pragma unroll
    for (int reg = 0; reg < 4; reg++) {
        int t = quad * 4 + reg;
        if (t < Tn)
            e_src[((size_t)bh * Tn + t) * Nn + i0 + l15] = acc[4][reg];
        else if (t < 2 * Tn)
            e_dst[((size_t)bh * Tn + (t - Tn)) * Nn + i0 + l15] = acc[4][reg];
    }
}

// ---------- kernel 2: attention partials — j split across blocks for full occupancy ----------
// grid: B * (N/16) * 2 = 1024 blocks x 512 threads; block = (i-tile, j-half of 512);
// wave = (head = w&3, j-quarter-of-tile = w>>2) -> per-wave j-range 256 = 2 chunks.
// j-split duplicates NOTHING heavy (adj/ed/B-frags are j-indexed) unlike i-splits (R14/R15).
// 4 blocks/CU (threads 2048, LDS 37.4K, VGPR ~44) = 32 waves/CU possible — 2x R16.
// Partials merge by addition (max-free softmax). Kept: no min-waves (R7), rolled chunk loop
// (R8), es2 broadcast + ed cndmask (R10/R12), l via 5th MFMA tile (R13), u8 adj (R16).
__global__ __launch_bounds__(512) void k_attn_partial(const unsigned char* __restrict__ adjp,
                                                      const float* __restrict__ e_src,
                                                      const float* __restrict__ e_dst,
                                                      const unsigned short* __restrict__ hT,
                                                      float* __restrict__ pacc,
                                                      float* __restrict__ pl) {
    __shared__ __align__(16) unsigned short p_lds[8][16][136];  // 34,816 B
    __shared__ float es2[4][16][8];
    __shared__ float l_lds[8][16];
    float* macc = (float*)&p_lds[4][0][0];  // [4 hh][16 r][64 e] f32 overlay

    int tid = threadIdx.x;
    int w = tid >> 6;
    int lane = tid & 63;
    int quad = lane >> 4;
    int l15 = lane & 15;
    int hh = w & 3;
    int half = w >> 2;
    int jb = blockIdx.x & 1;          // j-half of this block
    int tile = blockIdx.x >> 1;
    int b = tile >> 6;
    int i0 = (tile & 63) * 16;
    int bh = b * Hn + hh;
    int J0 = jb * 512 + half * 256;   // this wave's j-base; 2 chunks of 128

    const unsigned char* adj_base = adjp + ((size_t)(b * Nn + i0)) * Nn + J0;
    const float* edst = e_dst + (size_t)bh * Tn * Nn + J0;
    const unsigned short* hTb = hT + (size_t)bh * HOn * Nn;

    f32x4 acc[4] = {{0.f, 0.f, 0.f, 0.f}, {0.f, 0.f, 0.f, 0.f},
                    {0.f, 0.f, 0.f, 0.f}, {0.f, 0.f, 0.f, 0.f}};
    f32x4 accl = {0.f, 0.f, 0.f, 0.f};
    bf16x8 ONES;
    {
        short o = (short)0x3F80;  // bf16 1.0
        ONES = (bf16x8){o, o, o, o, o, o, o, o};
    }

    unsigned bufA[4], bufB[4];
#pragma unroll
    for (int r = 0; r < 4; r++)
        bufA[r] = *(const unsigned short*)(adj_base + (size_t)r * Nn + 2 * lane);

    if (w < 4) {
        const float* esrc = e_src + (size_t)bh * Tn * Nn;
#pragma unroll
        for (int idx = lane; idx < 80; idx += 64) {
            int t = idx >> 4, row = idx & 15;
            es2[w][row][t] = esrc[t * Nn + i0 + row];
        }
    }
    __syncthreads();

#define P1ROW(ROW, AV)                                                          \
    {                                                                           \
        int a0 = (int)((AV) & 0xFFu);                                           \
        int a1 = (int)(((AV) >> 8) & 0xFFu);                                    \
        int t0 = a0 - 1; t0 = (t0 < 0) ? 0 : t0;                                \
        int t1 = a1 - 1; t1 = (t1 < 0) ? 0 : t1;                                \
        float e0 = es2[hh][ROW][t0];                                            \
        float e1 = es2[hh][ROW][t1];                                            \
        float d0 = edc[0].x, d1 = edc[0].y;                                     \
        d0 = (t0 == 1) ? edc[1].x : d0; d1 = (t1 == 1) ? edc[1].y : d1;         \
        d0 = (t0 == 2) ? edc[2].x : d0; d1 = (t1 == 2) ? edc[2].y : d1;         \
        d0 = (t0 == 3) ? edc[3].x : d0; d1 = (t1 == 3) ? edc[3].y : d1;         \
        d0 = (t0 == 4) ? edc[4].x : d0; d1 = (t1 == 4) ? edc[4].y : d1;         \
        float x0 = e0 + d0; x0 = fmaxf(x0, 0.01f * x0);                         \
        float x1 = e1 + d1; x1 = fmaxf(x1, 0.01f * x1);                         \
        float p0 = __expf(x0); p0 = (a0 == 0) ? 0.f : p0;                       \
        float p1 = __expf(x1); p1 = (a1 == 0) ? 0.f : p1;                       \
        __hip_bfloat162 pp = __float22bfloat162_rn(make_float2(p0, p1));        \
        unsigned pu; __builtin_memcpy(&pu, &pp, 4);                             \
        *(unsigned*)(&p_lds[w][ROW][2 * lane]) = pu;                            \
    }

#pragma unroll 1
    for (int c = 0; c < 2; c++) {
        int jc = c * 128;
        float2 edc[Tn];
#pragma unroll
        for (int t = 0; t < Tn; t++) edc[t] = *(const float2*)(edst + t * Nn + jc + 2 * lane);
#pragma unroll
        for (int r = 0; r < 4; r++)
            bufB[r] = *(const unsigned short*)(adj_base + (size_t)(4 + r) * Nn + jc + 2 * lane);
#pragma unroll
        for (int r = 0; r < 4; r++) P1ROW(r, bufA[r]);
#pragma unroll
        for (int r = 0; r < 4; r++)
            bufA[r] = *(const unsigned short*)(adj_base + (size_t)(8 + r) * Nn + jc + 2 * lane);
#pragma unroll
        for (int r = 0; r < 4; r++) P1ROW(4 + r, bufB[r]);
#pragma unroll
        for (int r = 0; r < 4; r++)
            bufB[r] = *(const unsigned short*)(adj_base + (size_t)(12 + r) * Nn + jc + 2 * lane);
#pragma unroll
        for (int r = 0; r < 4; r++) P1ROW(8 + r, bufA[r]);
        if (c < 1) {
#pragma unroll
            for (int r = 0; r < 4; r++)
                bufA[r] = *(const unsigned short*)(adj_base + (size_t)r * Nn + jc + 128 + 2 * lane);
        }
#pragma unroll
        for (int r = 0; r < 4; r++) P1ROW(12 + r, bufB[r]);
#pragma unroll
        for (int k = 0; k < 4; k++) {
            bf16x8 Afr = *(const bf16x8*)(&p_lds[w][l15][k * 32 + quad * 8]);
            accl = __builtin_amdgcn_mfma_f32_16x16x32_bf16(Afr, ONES, accl, 0, 0, 0);
#pragma unroll
            for (int et = 0; et < 4; et++) {
                bf16x8 Bf = *(const bf16x8*)(hTb + (size_t)(et * 16 + l15) * Nn + J0 + jc + k * 32 + quad * 8);
                acc[et] = __builtin_amdgcn_mfma_f32_16x16x32_bf16(Afr, Bf, acc[et], 0, 0, 0);
            }
        }
    }
#undef P1ROW

    if (l15 == 0) {
#pragma unroll
        for (int reg = 0; reg < 4; reg++) l_lds[w][quad * 4 + reg] = accl[reg];
    }
    __syncthreads();
    if (w >= 4) {
#pragma unroll
        for (int et = 0; et < 4; et++)
#pragma unroll
            for (int reg = 0; reg < 4; reg++)
                macc[((hh * 16) + quad * 4 + reg) * 64 + et * 16 + l15] = acc[et][reg];
        __syncthreads();
        return;
    }
    __syncthreads();

    // write partials (coalesced 16-lane f32 runs): O-partial and l-partial
    size_t pbase = ((size_t)(tile * 2 + jb) * Hn + hh) * 16;
#pragma unroll
    for (int reg = 0; reg < 4; reg++) {
        int r = quad * 4 + reg;
        if (l15 == 0) pl[pbase + r] = l_lds[w][r] + l_lds[w + 4][r];
#pragma unroll
        for (int et = 0; et < 4; et++) {
            float v = acc[et][reg] + macc[((hh * 16) + r) * 64 + et * 16 + l15];
            pacc[(pbase + r) * 64 + et * 16 + l15] = v;
        }
    }
}

// ---------- kernel 3: merge j-half partials + epilogue ----------
// grid: 512 blocks (i-tile) x 256 threads; wave = head, lane = e.
__global__ __launch_bounds__(256) void k_merge(const float* __restrict__ pacc,
                                               const float* __restrict__ pl,
                                               const unsigned short* __restrict__ hT,
                                               const float* __restrict__ bias,
                                               const float* __restrict__ gamma,
                                               const float* __restrict__ beta,
                                               float* __restrict__ out) {
    int tid = threadIdx.x;
    int hh = tid >> 6;
    int lane = tid & 63;  // = e
    int tile = blockIdx.x;
    int b = tile >> 6;
    int i0 = (tile & 63) * 16;
    int bh = b * Hn + hh;

    float bv = bias[hh * HOn + lane];
    float gv = gamma[hh * HOn + lane];
    float bev = beta[hh * HOn + lane];
    size_t p0 = ((size_t)(tile * 2 + 0) * Hn + hh) * 16;
    size_t p1 = ((size_t)(tile * 2 + 1) * Hn + hh) * 16;
    const unsigned short* hTb = hT + ((size_t)bh * HOn + lane) * Nn + i0;

#pragma unroll 4
    for (int r = 0; r < 16; r++) {
        float lw = pl[p0 + r] + pl[p1 + r];
        float linv = 1.f / fmaxf(lw, 1e-30f);
        float v = (pacc[(p0 + r) * 64 + lane] + pacc[(p1 + r) * 64 + lane]) * linv + bv;
        v = (v > 0.f) ? v : 0.f;
        v += b2f(hTb[r]);  // residual h (hT is L2-hot, strided over e)
        float s = v, ss = v * v;
#pragma unroll
        for (int off = 1; off < 64; off <<= 1) {
            s += __shfl_xor(s, off);
            ss += __shfl_xor(ss, off);
        }
        float mean = s * (1.f / 64.f);
        float var = ss * (1.f / 64.f) - mean * mean;
        float rstd = rsqrtf(var + 1e-6f);
        float o = (v - mean) * rstd * gv + bev;
        out[((size_t)(b * Nn + i0 + r)) * (Hn * HOn) + hh * HOn + lane] = o;
    }
}

extern "C" void kernel_launch(void* const* d_in, const int* in_sizes, int n_in,
                              void* d_out, int out_size, void* d_ws, size_t ws_size,
                              hipStream_t stream) {
    const float* X = (const float*)d_in[0];        // nodes_embed f32 [B,N,D]
    const int* adj = (const int*)d_in[1];          // node_adj int32 [B,N,N]
    const float* W = (const float*)d_in[2];        // [H,D,HO] f32
    const float* a_src = (const float*)d_in[3];    // [H,T,HO] f32
    const float* a_dst = (const float*)d_in[4];    // [H,T,HO] f32
    const float* bias = (const float*)d_in[5];     // [H,HO] f32
    const float* gamma = (const float*)d_in[6];    // [H,HO] f32
    const float* beta = (const float*)d_in[7];     // [H,HO] f32
    float* out = (float*)d_out;                    // [B,N,H*HO] f32

    char* ws = (char*)d_ws;
    size_t off = 0;
    unsigned short* hT = (unsigned short*)(ws + off);  off += (size_t)Bn * Hn * Nn * HOn * 2;  // 4 MB
    unsigned short* WT = (unsigned short*)(ws + off);  off += (size_t)Hn * WTR * Dn * 2;       // 160 KB
    float* e_src = (float*)(ws + off);                 off += (size_t)Bn * Hn * Tn * Nn * 4;   // 640 KB
    float* e_dst = (float*)(ws + off);                 off += (size_t)Bn * Hn * Tn * Nn * 4;   // 640 KB
    unsigned char* adjp = (unsigned char*)(ws + off);  off += (size_t)Bn * Nn * Nn;            // 8 MB
    float* pacc = (float*)(ws + off);                  off += (size_t)1024 * Hn * 16 * 64 * 4; // 16.8 MB
    float* pl = (float*)(ws + off);                    off += (size_t)1024 * Hn * 16 * 4;      // 256 KB

    if (ws_size < off) {
        k_signal<<<(out_size + 255) / 256, 256, 0, stream>>>(out, out_size);
        return;
    }

    k_transpose_w<<<Hn * (Dn / 64), 256, 0, stream>>>(W, a_src, a_dst, WT);
    k_proj<<<Bn * (Nn / 16), 256, 0, stream>>>(X, WT, adj, hT, e_src, e_dst, (unsigned*)adjp);
    k_attn_partial<<<Bn * (Nn / 16) * 2, 512, 0, stream>>>(adjp, e_src, e_dst, hT, pacc, pl);
    k_merge<<<Bn * (Nn / 16), 256, 0, stream>>>(pacc, pl, hT, bias, gamma, beta, out);
}

// Round 18
// 150.978 us; speedup vs baseline: 1.0721x; 1.0721x over previous
//
#include <hip/hip_runtime.h>
#include <hip/hip_bf16.h>

#define Bn 8
#define Nn 1024
#define Dn 256
#define Hn 4
#define HOn 64
#define Tn 5
#define WTR 80   // WT rows per head: 64 W^T cols + 10 Wa rows + 6 zero pad

typedef short bf16x8 __attribute__((ext_vector_type(8)));
typedef float f32x4 __attribute__((ext_vector_type(4)));

__device__ __forceinline__ float b2f(unsigned short u) {
    unsigned x = ((unsigned)u) << 16;
    float f;
    __builtin_memcpy(&f, &x, 4);
    return f;
}
__device__ __forceinline__ unsigned bfr(float f) {
    unsigned u;
    __builtin_memcpy(&u, &f, 4);
    return (u + 0x7FFFu + ((u >> 16) & 1u)) >> 16;
}
__device__ __forceinline__ unsigned short f2b(float f) { return (unsigned short)bfr(f); }

// ---------- fallback: signal "workspace too small" with out = 100.0 ----------
__global__ __launch_bounds__(256) void k_signal(float* __restrict__ out, int n) {
    int i = blockIdx.x * 256 + threadIdx.x;
    if (i < n) out[i] = 100.0f;
}

// ---------- kernel 0: WT [H][80][D] bf16: rows 0-63 = W^T, 64-73 = W.a_src|W.a_dst, 74-79 = 0
__global__ __launch_bounds__(256) void k_transpose_w(const float* __restrict__ W,
                                                     const float* __restrict__ a_src,
                                                     const float* __restrict__ a_dst,
                                                     unsigned short* __restrict__ WT) {
    __shared__ float tile[64][65];
    int h = blockIdx.x >> 2;
    int d0 = (blockIdx.x & 3) * 64;
    int c0 = threadIdx.x & 63;
    int r0 = threadIdx.x >> 6;  // 0..3
#pragma unroll
    for (int r = 0; r < 16; r++) {
        int d = r * 4 + r0;
        tile[d][c0] = W[((size_t)(h * Dn + d0 + d)) * HOn + c0];  // coalesced over e
    }
    __syncthreads();
#pragma unroll
    for (int r = 0; r < 16; r++) {
        int e = r * 4 + r0;
        WT[((size_t)(h * WTR + e)) * Dn + d0 + c0] = f2b(tile[c0][e]);
    }
    for (int t = r0; t < 2 * Tn; t += 4) {
        const float* av = (t < Tn) ? (a_src + (h * Tn + t) * HOn)
                                   : (a_dst + (h * Tn + t - Tn) * HOn);
        float s = 0.f;
#pragma unroll
        for (int e = 0; e < HOn; e++) s += tile[c0][e] * av[e];
        WT[((size_t)(h * WTR + 64 + t)) * Dn + d0 + c0] = f2b(s);
    }
    for (int rr = 74 + r0; rr < WTR; rr += 4)
        WT[((size_t)(h * WTR + rr)) * Dn + d0 + c0] = 0;
}

// ---------- kernel 1: h^T = W^T x X^T via MFMA + adj u8 packing ----------
__global__ __launch_bounds__(256) void k_proj(const float* __restrict__ X,
                                              const unsigned short* __restrict__ WT,
                                              const int* __restrict__ adj,
                                              unsigned short* __restrict__ hT,
                                              float* __restrict__ e_src,
                                              float* __restrict__ e_dst,
                                              unsigned* __restrict__ adjp) {
    int tid = threadIdx.x;
    int w = tid >> 6;
    int lane = tid & 63;
    int quad = lane >> 4;
    int l15 = lane & 15;
    int b = blockIdx.x >> 6;
    int i0 = (blockIdx.x & 63) * 16;
    int h = w;
    int bh = b * Hn + h;

    // pack this block's 16 adj rows to u8 (coalesced int4 loads / u32 stores)
    {
        const int* arow = adj + ((size_t)(b * Nn + i0)) * Nn;
        unsigned* aout = adjp + ((size_t)(b * Nn + i0)) * Nn / 4;
#pragma unroll 4
        for (int k = 0; k < 16; k++) {
            int idx = tid + k * 256;
            int4 v = *(const int4*)(arow + (size_t)idx * 4);
            unsigned pk = (unsigned)(v.x & 0xFF) | ((unsigned)(v.y & 0xFF) << 8) |
                          ((unsigned)(v.z & 0xFF) << 16) | ((unsigned)(v.w & 0xFF) << 24);
            aout[idx] = pk;
        }
    }

    bf16x8 Bx[8];
    const float* xf = X + ((size_t)(b * Nn + i0 + l15)) * Dn + quad * 8;
#pragma unroll
    for (int kc = 0; kc < 8; kc++) {
        union { bf16x8 v; unsigned u[4]; } uu;
        const float4* xp = (const float4*)(xf + kc * 32);
        float4 A0 = xp[0], A1 = xp[1];
        __hip_bfloat162 h0 = __float22bfloat162_rn(make_float2(A0.x, A0.y));
        __hip_bfloat162 h1 = __float22bfloat162_rn(make_float2(A0.z, A0.w));
        __hip_bfloat162 h2 = __float22bfloat162_rn(make_float2(A1.x, A1.y));
        __hip_bfloat162 h3 = __float22bfloat162_rn(make_float2(A1.z, A1.w));
        __builtin_memcpy(&uu.u[0], &h0, 4);
        __builtin_memcpy(&uu.u[1], &h1, 4);
        __builtin_memcpy(&uu.u[2], &h2, 4);
        __builtin_memcpy(&uu.u[3], &h3, 4);
        Bx[kc] = uu.v;
    }

    f32x4 acc[5] = {{0.f, 0.f, 0.f, 0.f}, {0.f, 0.f, 0.f, 0.f}, {0.f, 0.f, 0.f, 0.f},
                    {0.f, 0.f, 0.f, 0.f}, {0.f, 0.f, 0.f, 0.f}};
    const unsigned short* wbase = WT + (size_t)h * WTR * Dn;
#pragma unroll
    for (int kc = 0; kc < 8; kc++) {
#pragma unroll
        for (int et = 0; et < 5; et++) {
            bf16x8 Aw = *(const bf16x8*)(wbase + (size_t)(et * 16 + l15) * Dn + kc * 32 + quad * 8);
            acc[et] = __builtin_amdgcn_mfma_f32_16x16x32_bf16(Aw, Bx[kc], acc[et], 0, 0, 0);
        }
    }

#pragma unroll
    for (int et = 0; et < 4; et++) {
#pragma unroll
        for (int reg = 0; reg < 4; reg++) {
            int e = et * 16 + quad * 4 + reg;
            hT[((size_t)bh * HOn + e) * Nn + i0 + l15] = f2b(acc[et][reg]);
        }
    }
#pragma unroll
    for (int reg = 0; reg < 4; reg++) {
        int t = quad * 4 + reg;
        if (t < Tn)
            e_src[((size_t)bh * Tn + t) * Nn + i0 + l15] = acc[4][reg];
        else if (t < 2 * Tn)
            e_dst[((size_t)bh * Tn + (t - Tn)) * Nn + i0 + l15] = acc[4][reg];
    }
}

// ---------- kernel 2: fused attention — R16 structure + ed register prefetch ----------
// grid: B * (N/16) = 512 blocks x 512 threads (8 waves); wave = (head = w&3, j-half = w>>2).
// R16 baseline (47 us) + next-chunk ed prefetched into regs mid-chunk (chunk-top L2 stall
// removed; +10 VGPR, ~54 <= 64 keeps 8 waves/SIMD). R17 proved the occupancy ceiling (~35-40%)
// is allocation-side: j-split to 4 blocks/CU did NOT raise residency — grid/block shape here
// is the optimum. Kept: no min-waves (R7 spill); rolled chunk loop (R8 spill); es2 broadcast
// + ed cndmask (R10/R12); l via 5th MFMA tile (R13); u8 L2-resident adj (R16);
// never split i across blocks/waves (R11/R14/R15).
__global__ __launch_bounds__(512) void k_attn(const unsigned char* __restrict__ adjp,
                                              const float* __restrict__ e_src,
                                              const float* __restrict__ e_dst,
                                              const unsigned short* __restrict__ hT,
                                              const float* __restrict__ bias,
                                              const float* __restrict__ gamma,
                                              const float* __restrict__ beta,
                                              float* __restrict__ out) {
    __shared__ __align__(16) unsigned short p_lds[8][16][136];  // 34,816 B
    __shared__ float es2[4][16][8];                             // [hh][row][t] broadcast
    __shared__ float l_lds[8][16];
    float* macc = (float*)&p_lds[4][0][0];  // [4 hh][16 r][64 e] f32 overlay (16,384 B)

    int tid = threadIdx.x;
    int w = tid >> 6;
    int lane = tid & 63;
    int quad = lane >> 4;
    int l15 = lane & 15;
    int hh = w & 3;
    int half = w >> 2;
    int b = blockIdx.x >> 6;
    int i0 = (blockIdx.x & 63) * 16;
    int bh = b * Hn + hh;
    int J0 = half * 512;

    const unsigned char* adj_base = adjp + ((size_t)(b * Nn + i0)) * Nn + J0;
    const float* edst = e_dst + (size_t)bh * Tn * Nn + J0;
    const unsigned short* hTb = hT + (size_t)bh * HOn * Nn;

    f32x4 acc[4] = {{0.f, 0.f, 0.f, 0.f}, {0.f, 0.f, 0.f, 0.f},
                    {0.f, 0.f, 0.f, 0.f}, {0.f, 0.f, 0.f, 0.f}};
    f32x4 accl = {0.f, 0.f, 0.f, 0.f};  // l row-sums via MFMA with B = ones
    bf16x8 ONES;
    {
        short o = (short)0x3F80;  // bf16 1.0
        ONES = (bf16x8){o, o, o, o, o, o, o, o};
    }

    // prefetch adj rows 0-3 of chunk 0 (u16 = 2 adj bytes per lane) + ed chunk 0
    unsigned bufA[4], bufB[4];
#pragma unroll
    for (int r = 0; r < 4; r++)
        bufA[r] = *(const unsigned short*)(adj_base + (size_t)r * Nn + 2 * lane);
    float2 edc[Tn], edn[Tn];
#pragma unroll
    for (int t = 0; t < Tn; t++) edc[t] = *(const float2*)(edst + t * Nn + 2 * lane);

    // es2[hh][row][t] staging (waves 0-3)
    if (w < 4) {
        const float* esrc = e_src + (size_t)bh * Tn * Nn;
#pragma unroll
        for (int idx = lane; idx < 80; idx += 64) {
            int t = idx >> 4, row = idx & 15;
            es2[w][row][t] = esrc[t * Nn + i0 + row];
        }
    }
    __syncthreads();

// pass-1: p = exp(leakyrelu(es2[row][t] + ed_sel)), masked -> 0.
// es: LDS broadcast (fixed row -> 5 distinct banks, conflict-free); ed: cndmask on edc regs.
#define P1ROW(ROW, AV)                                                          \
    {                                                                           \
        int a0 = (int)((AV) & 0xFFu);                                           \
        int a1 = (int)(((AV) >> 8) & 0xFFu);                                    \
        int t0 = a0 - 1; t0 = (t0 < 0) ? 0 : t0;                                \
        int t1 = a1 - 1; t1 = (t1 < 0) ? 0 : t1;                                \
        float e0 = es2[hh][ROW][t0];                                            \
        float e1 = es2[hh][ROW][t1];                                            \
        float d0 = edc[0].x, d1 = edc[0].y;                                     \
        d0 = (t0 == 1) ? edc[1].x : d0; d1 = (t1 == 1) ? edc[1].y : d1;         \
        d0 = (t0 == 2) ? edc[2].x : d0; d1 = (t1 == 2) ? edc[2].y : d1;         \
        d0 = (t0 == 3) ? edc[3].x : d0; d1 = (t1 == 3) ? edc[3].y : d1;         \
        d0 = (t0 == 4) ? edc[4].x : d0; d1 = (t1 == 4) ? edc[4].y : d1;         \
        float x0 = e0 + d0; x0 = fmaxf(x0, 0.01f * x0);                         \
        float x1 = e1 + d1; x1 = fmaxf(x1, 0.01f * x1);                         \
        float p0 = __expf(x0); p0 = (a0 == 0) ? 0.f : p0;                       \
        float p1 = __expf(x1); p1 = (a1 == 0) ? 0.f : p1;                       \
        __hip_bfloat162 pp = __float22bfloat162_rn(make_float2(p0, p1));        \
        unsigned pu; __builtin_memcpy(&pu, &pp, 4);                             \
        *(unsigned*)(&p_lds[w][ROW][2 * lane]) = pu;                            \
    }

#pragma unroll 1
    for (int c = 0; c < 4; c++) {
        int jc = c * 128;  // relative to J0
        // rolling 4-row adj buffers (L2 hits, covered by a 4-row pass-1 group)
#pragma unroll
        for (int r = 0; r < 4; r++)
            bufB[r] = *(const unsigned short*)(adj_base + (size_t)(4 + r) * Nn + jc + 2 * lane);
#pragma unroll
        for (int r = 0; r < 4; r++) P1ROW(r, bufA[r]);
#pragma unroll
        for (int r = 0; r < 4; r++)
            bufA[r] = *(const unsigned short*)(adj_base + (size_t)(8 + r) * Nn + jc + 2 * lane);
        // next chunk's ed prefetch (consumed next iteration -> full chunk of latency cover)
        if (c < 3) {
#pragma unroll
            for (int t = 0; t < Tn; t++)
                edn[t] = *(const float2*)(edst + t * Nn + jc + 128 + 2 * lane);
        }
#pragma unroll
        for (int r = 0; r < 4; r++) P1ROW(4 + r, bufB[r]);
#pragma unroll
        for (int r = 0; r < 4; r++)
            bufB[r] = *(const unsigned short*)(adj_base + (size_t)(12 + r) * Nn + jc + 2 * lane);
#pragma unroll
        for (int r = 0; r < 4; r++) P1ROW(8 + r, bufA[r]);
        if (c < 3) {
#pragma unroll
            for (int r = 0; r < 4; r++)
                bufA[r] = *(const unsigned short*)(adj_base + (size_t)r * Nn + jc + 128 + 2 * lane);
        }
#pragma unroll
        for (int r = 0; r < 4; r++) P1ROW(12 + r, bufB[r]);
        // PV via MFMA: A = P (own-wave LDS, b128); 5th tile (B=ones) accumulates l row-sums
#pragma unroll
        for (int k = 0; k < 4; k++) {
            bf16x8 Afr = *(const bf16x8*)(&p_lds[w][l15][k * 32 + quad * 8]);
            accl = __builtin_amdgcn_mfma_f32_16x16x32_bf16(Afr, ONES, accl, 0, 0, 0);
#pragma unroll
            for (int et = 0; et < 4; et++) {
                bf16x8 Bf = *(const bf16x8*)(hTb + (size_t)(et * 16 + l15) * Nn + J0 + jc + k * 32 + quad * 8);
                acc[et] = __builtin_amdgcn_mfma_f32_16x16x32_bf16(Afr, Bf, acc[et], 0, 0, 0);
            }
        }
        // promote prefetched ed
        if (c < 3) {
#pragma unroll
            for (int t = 0; t < Tn; t++) edc[t] = edn[t];
        }
    }
#undef P1ROW

    // l: accl[reg] (any l15 col) = row-sum for row quad*4+reg
    if (l15 == 0) {
#pragma unroll
        for (int reg = 0; reg < 4; reg++) l_lds[w][quad * 4 + reg] = accl[reg];
    }
    __syncthreads();  // all waves done with p_lds (MFMA reads) before macc overlay
    if (w >= 4) {
#pragma unroll
        for (int et = 0; et < 4; et++)
#pragma unroll
            for (int reg = 0; reg < 4; reg++)
                macc[((hh * 16) + quad * 4 + reg) * 64 + et * 16 + l15] = acc[et][reg];
    }
    __syncthreads();
    if (w >= 4) return;

    // merge + epilogue: /l, +bias, relu, +h, LayerNorm over HO, store f32
    float bv[4], gv[4], bev[4];
#pragma unroll
    for (int et = 0; et < 4; et++) {
        int e = et * 16 + l15;
        bv[et] = bias[hh * HOn + e];
        gv[et] = gamma[hh * HOn + e];
        bev[et] = beta[hh * HOn + e];
    }
#pragma unroll
    for (int reg = 0; reg < 4; reg++) {
        int r = quad * 4 + reg;
        int i = i0 + r;
        float lw = l_lds[w][r] + l_lds[w + 4][r];
        float linv = 1.f / fmaxf(lw, 1e-30f);
        float dv[4];
        float s = 0.f, ss = 0.f;
#pragma unroll
        for (int et = 0; et < 4; et++) {
            int e = et * 16 + l15;
            float v = (acc[et][reg] + macc[((hh * 16) + r) * 64 + e]) * linv + bv[et];
            v = (v > 0.f) ? v : 0.f;
            v += b2f(hTb[(size_t)e * Nn + i]);  // residual h
            dv[et] = v;
            s += v;
            ss += v * v;
        }
#pragma unroll
        for (int off = 8; off; off >>= 1) {
            s += __shfl_xor(s, off);
            ss += __shfl_xor(ss, off);
        }
        float mean = s * (1.f / 64.f);
        float var = ss * (1.f / 64.f) - mean * mean;
        float rstd = rsqrtf(var + 1e-6f);
#pragma unroll
        for (int et = 0; et < 4; et++) {
            int e = et * 16 + l15;
            float o = (dv[et] - mean) * rstd * gv[et] + bev[et];
            out[((size_t)(b * Nn + i)) * (Hn * HOn) + hh * HOn + e] = o;
        }
    }
}

extern "C" void kernel_launch(void* const* d_in, const int* in_sizes, int n_in,
                              void* d_out, int out_size, void* d_ws, size_t ws_size,
                              hipStream_t stream) {
    const float* X = (const float*)d_in[0];        // nodes_embed f32 [B,N,D]
    const int* adj = (const int*)d_in[1];          // node_adj int32 [B,N,N]
    const float* W = (const float*)d_in[2];        // [H,D,HO] f32
    const float* a_src = (const float*)d_in[3];    // [H,T,HO] f32
    const float* a_dst = (const float*)d_in[4];    // [H,T,HO] f32
    const float* bias = (const float*)d_in[5];     // [H,HO] f32
    const float* gamma = (const float*)d_in[6];    // [H,HO] f32
    const float* beta = (const float*)d_in[7];     // [H,HO] f32
    float* out = (float*)d_out;                    // [B,N,H*HO] f32

    char* ws = (char*)d_ws;
    size_t off = 0;
    unsigned short* hT = (unsigned short*)(ws + off);  off += (size_t)Bn * Hn * Nn * HOn * 2;  // 4 MB
    unsigned short* WT = (unsigned short*)(ws + off);  off += (size_t)Hn * WTR * Dn * 2;       // 160 KB
    float* e_src = (float*)(ws + off);                 off += (size_t)Bn * Hn * Tn * Nn * 4;   // 640 KB
    float* e_dst = (float*)(ws + off);                 off += (size_t)Bn * Hn * Tn * Nn * 4;   // 640 KB
    unsigned char* adjp = (unsigned char*)(ws + off);  off += (size_t)Bn * Nn * Nn;            // 8 MB

    if (ws_size < off) {
        k_signal<<<(out_size + 255) / 256, 256, 0, stream>>>(out, out_size);
        return;
    }

    k_transpose_w<<<Hn * (Dn / 64), 256, 0, stream>>>(W, a_src, a_dst, WT);
    k_proj<<<Bn * (Nn / 16), 256, 0, stream>>>(X, WT, adj, hT, e_src, e_dst, (unsigned*)adjp);
    k_attn<<<Bn * (Nn / 16), 512, 0, stream>>>(adjp, e_src, e_dst, hT, bias, gamma, beta, out);
}